// Round 4
// baseline (1007.929 us; speedup 1.0000x reference)
//
#include <hip/hip_runtime.h>
#include <hip/hip_bf16.h>

#define T_TOK 2048
#define D_DIM 1024
#define H_DIM 2816
#define E_NUM 8
#define CAP   1024             // per-expert row capacity (mean load 512, ~24 sigma margin)

typedef __attribute__((ext_vector_type(8))) short short8;
typedef __attribute__((ext_vector_type(4))) float floatx4;

__device__ __forceinline__ unsigned short f2bf(float f) {
    unsigned int b = __float_as_uint(f);
    b += 0x7FFFu + ((b >> 16) & 1u);   // round-to-nearest-even
    return (unsigned short)(b >> 16);
}

// pack 2 f32 -> 2 bf16 in one v_perm (round-half-up via +0x8000)
__device__ __forceinline__ unsigned pk2(float lo, float hi) {
    unsigned a = __float_as_uint(lo) + 0x8000u;
    unsigned b = __float_as_uint(hi) + 0x8000u;
    return __builtin_amdgcn_perm(b, a, 0x07060302);
}

__device__ __forceinline__ short8 pack8r(float4 a, float4 b) {
    union { uint4 u; short8 s; } r;
    r.u.x = pk2(a.x, a.y);
    r.u.y = pk2(a.z, a.w);
    r.u.z = pk2(b.x, b.y);
    r.u.w = pk2(b.z, b.w);
    return r.s;
}

// async 16B global->LDS. LDS dest = wave-uniform base + lane*16.
__device__ __forceinline__ void gl2lds16(const void* g, void* l) {
    __builtin_amdgcn_global_load_lds(
        (const __attribute__((address_space(1))) unsigned int*)g,
        (__attribute__((address_space(3))) unsigned int*)l,
        16, 0, 0);
}

// Swizzled LDS tile layout (rows of 64 bf16 = 8 chunks of 16B), unpadded:
//   byte(row, slot) = (row>>3)*1024 + (row&7)*128 + slot*16
//   content(row, slot) = global chunk (slot ^ (row&7)).   0 bank conflicts (measured r2/r3).
// Pipeline (read-first, single buffer), per K-step:
//   ds_read frags(t) -> sync -> [B loads(t+1) FIRST, then gl2lds A(t+1)]
//   -> MFMA(t) -> pack/ds_write B(t+1) (vmcnt(8): only B retired, A stays in flight)
//   -> sync (drains A(t+1) under MFMA+pack cover)
// B-before-A issue order is load-bearing: vmcnt retires oldest-first, so if A were
// older the B-pack would force vmcnt(0) and drain the A prefetch early (r3 bug).

// ---- fused gate: logits -> softmax -> top2 -> scatter-gather x into slots ----
__global__ __launch_bounds__(256) void k_gate2(const float* __restrict__ x,
                                               const float* __restrict__ Wg,
                                               int* __restrict__ stok,
                                               float* __restrict__ sw,
                                               int* __restrict__ counts,
                                               unsigned short* __restrict__ xg) {
    const int wave = threadIdx.x >> 6, lane = threadIdx.x & 63;
    const int t = blockIdx.x * 4 + wave;
    const float* xr = x + (size_t)t * D_DIM;
    float acc[E_NUM];
#pragma unroll
    for (int e = 0; e < E_NUM; ++e) acc[e] = 0.f;
#pragma unroll 4
    for (int i = 0; i < D_DIM / 64; ++i) {
        float xv = xr[lane + 64 * i];
#pragma unroll
        for (int e = 0; e < E_NUM; ++e) acc[e] += xv * Wg[e * D_DIM + lane + 64 * i];
    }
#pragma unroll
    for (int e = 0; e < E_NUM; ++e) {
#pragma unroll
        for (int s = 32; s > 0; s >>= 1) acc[e] += __shfl_xor(acc[e], s, 64);
    }
    int slot0 = 0, slot1 = 0;
    if (lane == 0) {
        float mx = acc[0];
#pragma unroll
        for (int e = 1; e < E_NUM; ++e) mx = fmaxf(mx, acc[e]);
        float p[E_NUM], s = 0.f;
#pragma unroll
        for (int e = 0; e < E_NUM; ++e) { p[e] = __expf(acc[e] - mx); s += p[e]; }
        int i0 = 0;
#pragma unroll
        for (int e = 1; e < E_NUM; ++e) if (p[e] > p[i0]) i0 = e;
        int i1 = (i0 == 0) ? 1 : 0;
#pragma unroll
        for (int e = 0; e < E_NUM; ++e) if (e != i0 && p[e] > p[i1]) i1 = e;
        float s0 = p[i0] / s, s1 = p[i1] / s;
        float d = s0 + s1 + 1e-20f;
        int p0 = atomicAdd(&counts[i0], 1); if (p0 >= CAP) p0 = CAP - 1;
        int p1 = atomicAdd(&counts[i1], 1); if (p1 >= CAP) p1 = CAP - 1;
        slot0 = i0 * CAP + p0;
        slot1 = i1 * CAP + p1;
        stok[slot0] = t; sw[slot0] = s0 / d;
        stok[slot1] = t; sw[slot1] = s1 / d;
    }
    slot0 = __shfl(slot0, 0, 64);
    slot1 = __shfl(slot1, 0, 64);
    const float4* xr4 = (const float4*)xr;
    ushort4* xg4 = (ushort4*)xg;
#pragma unroll
    for (int it = 0; it < 4; ++it) {
        float4 v = xr4[lane + 64 * it];
        ushort4 o;
        o.x = f2bf(v.x); o.y = f2bf(v.y); o.z = f2bf(v.z); o.w = f2bf(v.w);
        xg4[(size_t)slot0 * 256 + lane + 64 * it] = o;
        xg4[(size_t)slot1 * 256 + lane + 64 * it] = o;
    }
}

// ---- GEMM 1&3: BM=256, BN=32(W1)+32(W3), BK=64, read-first pipeline, 4 blocks/CU ----
__global__ __launch_bounds__(256, 4) void k_gemm13(const unsigned short* __restrict__ xg,
                                                   const float* __restrict__ W1,
                                                   const float* __restrict__ W3,
                                                   const int* __restrict__ counts,
                                                   unsigned short* __restrict__ U) {
    const int nt = blockIdx.x;       // H/32 = 88
    const int mt = blockIdx.y;       // CAP/256 = 4
    const int e  = blockIdx.z;
    const int cnt = min(counts[e], CAP);
    if (mt * 256 >= cnt) return;

    __shared__ __align__(16) unsigned char As[32768];   // 256 rows x 64 bf16
    __shared__ __align__(16) unsigned char B1s[4096];   // 32 rows x 64 bf16
    __shared__ __align__(16) unsigned char B3s[4096];   // total 40960 B = 160KiB/4

    const int tid = threadIdx.x, lane = tid & 63, wave = tid >> 6;
    const int fr = lane & 15, quad = lane >> 4, f7 = fr & 7, f8 = fr >> 3;

    const unsigned short* aBase = xg
        + ((size_t)e * CAP + mt * 256 + wave * 64 + (lane >> 3)) * D_DIM
        + ((lane & 7) ^ (lane >> 3)) * 8;

    const int br = tid >> 3, bc = tid & 7;
    const float* w1p = W1 + ((size_t)e * H_DIM + nt * 32 + br) * D_DIM + bc * 8;
    const float* w3p = W3 + ((size_t)e * H_DIM + nt * 32 + br) * D_DIM + bc * 8;
    const int bslot = (br >> 3) * 1024 + (br & 7) * 128 + ((bc ^ (br & 7)) << 4);

    floatx4 acc1[4][2], acc3[4][2];
#pragma unroll
    for (int m = 0; m < 4; ++m)
#pragma unroll
        for (int n = 0; n < 2; ++n) { acc1[m][n] = (floatx4)0.f; acc3[m][n] = (floatx4)0.f; }

    const int agrp = (wave * 8 + f8) * 1024 + f7 * 128;
    const int c0 = (quad ^ f7) << 4;          // kk=0 chunk byte offset
    const int c1 = ((4 | quad) ^ f7) << 4;    // kk=1

    // ---- prologue: stage tile 0 ----
    {
        float4 u0 = *(const float4*)(w1p);
        float4 u1 = *(const float4*)(w1p + 4);
        float4 v0 = *(const float4*)(w3p);
        float4 v1 = *(const float4*)(w3p + 4);
#pragma unroll
        for (int j = 0; j < 8; ++j)
            gl2lds16(aBase + (size_t)j * 8 * D_DIM, As + (wave * 8 + j) * 1024);
        *(short8*)(B1s + bslot) = pack8r(u0, u1);
        *(short8*)(B3s + bslot) = pack8r(v0, v1);
    }
    __syncthreads();

#pragma unroll 1
    for (int t = 0; t < D_DIM / 64; ++t) {
        // ---- read ALL fragments of tile t into registers ----
        short8 a[4][2], b1[2][2], b3[2][2];
#pragma unroll
        for (int m = 0; m < 4; ++m) {
            const unsigned char* ab = As + agrp + m * 2048;
            a[m][0] = *(const short8*)(ab + c0);
            a[m][1] = *(const short8*)(ab + c1);
        }
#pragma unroll
        for (int n = 0; n < 2; ++n) {
            const int bg = (n * 2 + f8) * 1024 + f7 * 128;
            b1[n][0] = *(const short8*)(B1s + bg + c0);
            b1[n][1] = *(const short8*)(B1s + bg + c1);
            b3[n][0] = *(const short8*)(B3s + bg + c0);
            b3[n][1] = *(const short8*)(B3s + bg + c1);
        }
        __syncthreads();   // all waves done reading tile t (no vmem outstanding here)

        const bool more = (t < D_DIM / 64 - 1);
        float4 u0, u1, v0, v1;
        if (more) {
            const int kn = (t + 1) * 64;
            // B loads FIRST (oldest in vmcnt queue)...
            u0 = *(const float4*)(w1p + kn);
            u1 = *(const float4*)(w1p + kn + 4);
            v0 = *(const float4*)(w3p + kn);
            v1 = *(const float4*)(w3p + kn + 4);
            __builtin_amdgcn_sched_barrier(0);   // pin B-before-A issue order
            // ...then async A-stage (youngest; stays in flight through the pack)
#pragma unroll
            for (int j = 0; j < 8; ++j)
                gl2lds16(aBase + (size_t)j * 8 * D_DIM + kn, As + (wave * 8 + j) * 1024);
        }

        // ---- 32 MFMAs on registers (covers load latency above) ----
#pragma unroll
        for (int m = 0; m < 4; ++m) {
#pragma unroll
            for (int n = 0; n < 2; ++n) {
                acc1[m][n] = __builtin_amdgcn_mfma_f32_16x16x32_bf16(a[m][0], b1[n][0], acc1[m][n], 0, 0, 0);
                acc1[m][n] = __builtin_amdgcn_mfma_f32_16x16x32_bf16(a[m][1], b1[n][1], acc1[m][n], 0, 0, 0);
                acc3[m][n] = __builtin_amdgcn_mfma_f32_16x16x32_bf16(a[m][0], b3[n][0], acc3[m][n], 0, 0, 0);
                acc3[m][n] = __builtin_amdgcn_mfma_f32_16x16x32_bf16(a[m][1], b3[n][1], acc3[m][n], 0, 0, 0);
            }
        }

        if (more) {
            // needs only the 4 B loads retired -> vmcnt(8); gl2lds stays in flight
            *(short8*)(B1s + bslot) = pack8r(u0, u1);
            *(short8*)(B3s + bslot) = pack8r(v0, v1);
            __syncthreads();   // drains gl2lds; tile t+1 ready
        }
    }

#pragma unroll
    for (int m = 0; m < 4; ++m) {
#pragma unroll
        for (int r = 0; r < 4; ++r) {
            int g = mt * 256 + wave * 64 + m * 16 + quad * 4 + r;
            if (g < cnt) {
                size_t rowb = ((size_t)e * CAP + g) * H_DIM + nt * 32;
#pragma unroll
                for (int n = 0; n < 2; ++n) {
                    float u1v = acc1[m][n][r], u3v = acc3[m][n][r];
                    float u = u1v / (1.f + __expf(-u1v)) * u3v;
                    U[rowb + n * 16 + fr] = f2bf(u);
                }
            }
        }
    }
}

// ---- GEMM 2: BM=256, BN=64, BK=64, K=2816; read-first pipeline, 4 blocks/CU ----
__global__ __launch_bounds__(256, 4) void k_gemm2(const unsigned short* __restrict__ U,
                                                  const float* __restrict__ W2,
                                                  const int* __restrict__ counts,
                                                  const int* __restrict__ stok,
                                                  const float* __restrict__ sw,
                                                  float* __restrict__ y) {
    const int nt = blockIdx.x;       // D/64 = 16
    const int mt = blockIdx.y;       // CAP/256 = 4
    const int e  = blockIdx.z;
    const int cnt = min(counts[e], CAP);
    if (mt * 256 >= cnt) return;

    __shared__ __align__(16) unsigned char As[32768];   // 256 rows x 64 bf16
    __shared__ __align__(16) unsigned char Bs[8192];    // 64 w-rows; total 40960 B

    const int tid = threadIdx.x, lane = tid & 63, wave = tid >> 6;
    const int fr = lane & 15, quad = lane >> 4, f7 = fr & 7, f8 = fr >> 3;

    const unsigned short* aBase = U
        + ((size_t)e * CAP + mt * 256 + wave * 64 + (lane >> 3)) * H_DIM
        + ((lane & 7) ^ (lane >> 3)) * 8;

    const int br = tid >> 3, bc = tid & 7;       // rows br and br+32, chunk col bc
    const float* w2p0 = W2 + ((size_t)e * D_DIM + nt * 64 + br) * H_DIM + bc * 8;
    const float* w2p1 = w2p0 + (size_t)32 * H_DIM;
    const int bslot0 = (br >> 3) * 1024 + (br & 7) * 128 + ((bc ^ (br & 7)) << 4);
    const int bslot1 = bslot0 + 4096;            // (row+32)>>3 = +4 groups

    floatx4 acc[4][4];
#pragma unroll
    for (int m = 0; m < 4; ++m)
#pragma unroll
        for (int n = 0; n < 4; ++n) acc[m][n] = (floatx4)0.f;

    const int agrp = (wave * 8 + f8) * 1024 + f7 * 128;
    const int c0 = (quad ^ f7) << 4;
    const int c1 = ((4 | quad) ^ f7) << 4;

    // ---- prologue: stage tile 0 ----
    {
        float4 u0 = *(const float4*)(w2p0);
        float4 u1 = *(const float4*)(w2p0 + 4);
        float4 v0 = *(const float4*)(w2p1);
        float4 v1 = *(const float4*)(w2p1 + 4);
#pragma unroll
        for (int j = 0; j < 8; ++j)
            gl2lds16(aBase + (size_t)j * 8 * H_DIM, As + (wave * 8 + j) * 1024);
        *(short8*)(Bs + bslot0) = pack8r(u0, u1);
        *(short8*)(Bs + bslot1) = pack8r(v0, v1);
    }
    __syncthreads();

#pragma unroll 1
    for (int t = 0; t < H_DIM / 64; ++t) {
        // ---- read ALL fragments of tile t into registers ----
        short8 a[4][2], bf[4][2];
#pragma unroll
        for (int m = 0; m < 4; ++m) {
            const unsigned char* ab = As + agrp + m * 2048;
            a[m][0] = *(const short8*)(ab + c0);
            a[m][1] = *(const short8*)(ab + c1);
        }
#pragma unroll
        for (int n = 0; n < 4; ++n) {
            const int bg = (n * 2 + f8) * 1024 + f7 * 128;
            bf[n][0] = *(const short8*)(Bs + bg + c0);
            bf[n][1] = *(const short8*)(Bs + bg + c1);
        }
        __syncthreads();   // all waves done reading tile t

        const bool more = (t < H_DIM / 64 - 1);
        float4 u0, u1, v0, v1;
        if (more) {
            const int kn = (t + 1) * 64;
            // B loads FIRST (oldest), then gl2lds (youngest) — see header comment
            u0 = *(const float4*)(w2p0 + kn);
            u1 = *(const float4*)(w2p0 + kn + 4);
            v0 = *(const float4*)(w2p1 + kn);
            v1 = *(const float4*)(w2p1 + kn + 4);
            __builtin_amdgcn_sched_barrier(0);
#pragma unroll
            for (int j = 0; j < 8; ++j)
                gl2lds16(aBase + (size_t)j * 8 * H_DIM + kn, As + (wave * 8 + j) * 1024);
        }

        // ---- 32 MFMAs on registers ----
#pragma unroll
        for (int m = 0; m < 4; ++m) {
#pragma unroll
            for (int n = 0; n < 4; ++n) {
                acc[m][n] = __builtin_amdgcn_mfma_f32_16x16x32_bf16(a[m][0], bf[n][0], acc[m][n], 0, 0, 0);
                acc[m][n] = __builtin_amdgcn_mfma_f32_16x16x32_bf16(a[m][1], bf[n][1], acc[m][n], 0, 0, 0);
            }
        }

        if (more) {
            *(short8*)(Bs + bslot0) = pack8r(u0, u1);   // vmcnt(8): B only
            *(short8*)(Bs + bslot1) = pack8r(v0, v1);
            __syncthreads();   // drains gl2lds; tile t+1 ready
        }
    }

#pragma unroll
    for (int m = 0; m < 4; ++m) {
#pragma unroll
        for (int r = 0; r < 4; ++r) {
            int g = mt * 256 + wave * 64 + m * 16 + quad * 4 + r;
            if (g < cnt) {
                int slot = e * CAP + g;
                int t = stok[slot];
                float w = sw[slot];
                float* yr = y + (size_t)t * D_DIM + nt * 64;
#pragma unroll
                for (int n = 0; n < 4; ++n)
                    atomicAdd(&yr[n * 16 + fr], w * acc[m][n][r]);
            }
        }
    }
}

// ---------------- workspace layout ----------------
static const size_t OFF_XG   = 0;                                   // 8*CAP*D*2 = 16,777,216
static const size_t OFF_U    = (size_t)E_NUM * CAP * D_DIM * 2;     // 8*CAP*H*2 = 46,137,344
static const size_t OFF_STOK = OFF_U + (size_t)E_NUM * CAP * H_DIM * 2;
static const size_t OFF_SW   = OFF_STOK + (size_t)E_NUM * CAP * 4;
static const size_t OFF_META = OFF_SW + (size_t)E_NUM * CAP * 4;

extern "C" void kernel_launch(void* const* d_in, const int* in_sizes, int n_in,
                              void* d_out, int out_size, void* d_ws, size_t ws_size,
                              hipStream_t stream) {
    const float* x  = (const float*)d_in[0];
    const float* Wg = (const float*)d_in[1];
    const float* W1 = (const float*)d_in[2];
    const float* W2 = (const float*)d_in[3];
    const float* W3 = (const float*)d_in[4];
    float* y = (float*)d_out;
    char* ws = (char*)d_ws;

    unsigned short* xg = (unsigned short*)(ws + OFF_XG);
    unsigned short* U  = (unsigned short*)(ws + OFF_U);
    int*   stok   = (int*)(ws + OFF_STOK);
    float* sw     = (float*)(ws + OFF_SW);
    int*   counts = (int*)(ws + OFF_META);

    hipMemsetAsync(counts, 0, 64, stream);
    hipMemsetAsync(y, 0, (size_t)T_TOK * D_DIM * sizeof(float), stream);

    k_gate2<<<T_TOK / 4, 256, 0, stream>>>(x, Wg, stok, sw, counts, xg);
    k_gemm13<<<dim3(H_DIM / 32, CAP / 256, E_NUM), 256, 0, stream>>>(xg, W1, W3, counts, U);
    k_gemm2<<<dim3(D_DIM / 64, CAP / 256, E_NUM), 256, 0, stream>>>(U, W2, counts, stok, sw, y);
}

// Round 6
// 430.588 us; speedup vs baseline: 2.3408x; 2.3408x over previous
//
#include <hip/hip_runtime.h>
#include <hip/hip_bf16.h>

#define T_TOK 2048
#define D_DIM 1024
#define H_DIM 2816
#define E_NUM 8
#define CAP   1024             // per-expert row capacity (mean load 512, ~24 sigma margin)

#define NT13  (D_DIM / 64)     // 16 K-steps (even)
#define NT2   (H_DIM / 64)     // 44 K-steps (even)

typedef __attribute__((ext_vector_type(8))) short short8;
typedef __attribute__((ext_vector_type(4))) float floatx4;

__device__ __forceinline__ unsigned short f2bf(float f) {
    unsigned int b = __float_as_uint(f);
    b += 0x7FFFu + ((b >> 16) & 1u);   // round-to-nearest-even
    return (unsigned short)(b >> 16);
}

// pack 2 f32 -> 2 bf16 in one v_perm (round-half-up via +0x8000)
__device__ __forceinline__ unsigned pk2(float lo, float hi) {
    unsigned a = __float_as_uint(lo) + 0x8000u;
    unsigned b = __float_as_uint(hi) + 0x8000u;
    return __builtin_amdgcn_perm(b, a, 0x07060302);
}

__device__ __forceinline__ short8 pack8r(float4 a, float4 b) {
    union { uint4 u; short8 s; } r;
    r.u.x = pk2(a.x, a.y);
    r.u.y = pk2(a.z, a.w);
    r.u.z = pk2(b.x, b.y);
    r.u.w = pk2(b.z, b.w);
    return r.s;
}

// async 16B global->LDS. LDS dest = wave-uniform base + lane*16.
__device__ __forceinline__ void gl2lds16(const void* g, void* l) {
    __builtin_amdgcn_global_load_lds(
        (const __attribute__((address_space(1))) unsigned int*)g,
        (__attribute__((address_space(3))) unsigned int*)l,
        16, 0, 0);
}

#define WAIT_LGKM0 asm volatile("s_waitcnt lgkmcnt(0)" ::: "memory")
#define WAIT_VM(N) asm volatile("s_waitcnt vmcnt(" #N ")" ::: "memory")
#define SBAR       __builtin_amdgcn_s_barrier()
#define SCHED0     __builtin_amdgcn_sched_barrier(0)

// Swizzled LDS tile layout (rows of 64 bf16 = 8 chunks of 16B), unpadded:
//   byte(row, slot) = (row>>3)*1024 + (row&7)*128 + slot*16
//   content(row, slot) = global chunk (slot ^ (row&7)).   0 bank conflicts (measured r2/r3).
//
// Counted-vmcnt pipeline (T3/T4), per K-step:
//   ds_read frags(t) ; lgkmcnt(0) ; BARRIER#1        (all waves done reading tile t)
//   issue gl2lds A(t+1)  [8 ops, older]
//   issue Bload(t+2)->regs [4 ops, newer]            (B = HBM-streamed weights: 2-deep)
//   MFMA(t) x32                                      (covers load latency)
//   pack/ds_write B(t+1) (regs loaded 2 steps ago: no stall)
//   vmcnt(4) [A staged; B(t+2) stays IN FLIGHT across the barrier] ; lgkmcnt(0) ; BARRIER#2
// Never vmcnt(0) in the main loop. Issue order gl2lds-before-Bload is load-bearing
// (vmcnt retires oldest-first; vmcnt(4) must leave exactly the 4 B-loads).

// ---- fused gate: logits -> softmax -> top2 -> scatter-gather x into slots ----
__global__ __launch_bounds__(256) void k_gate2(const float* __restrict__ x,
                                               const float* __restrict__ Wg,
                                               int* __restrict__ stok,
                                               float* __restrict__ sw,
                                               int* __restrict__ counts,
                                               unsigned short* __restrict__ xg) {
    const int wave = threadIdx.x >> 6, lane = threadIdx.x & 63;
    const int t = blockIdx.x * 4 + wave;
    const float* xr = x + (size_t)t * D_DIM;
    float acc[E_NUM];
#pragma unroll
    for (int e = 0; e < E_NUM; ++e) acc[e] = 0.f;
#pragma unroll 4
    for (int i = 0; i < D_DIM / 64; ++i) {
        float xv = xr[lane + 64 * i];
#pragma unroll
        for (int e = 0; e < E_NUM; ++e) acc[e] += xv * Wg[e * D_DIM + lane + 64 * i];
    }
#pragma unroll
    for (int e = 0; e < E_NUM; ++e) {
#pragma unroll
        for (int s = 32; s > 0; s >>= 1) acc[e] += __shfl_xor(acc[e], s, 64);
    }
    int slot0 = 0, slot1 = 0;
    if (lane == 0) {
        float mx = acc[0];
#pragma unroll
        for (int e = 1; e < E_NUM; ++e) mx = fmaxf(mx, acc[e]);
        float p[E_NUM], s = 0.f;
#pragma unroll
        for (int e = 0; e < E_NUM; ++e) { p[e] = __expf(acc[e] - mx); s += p[e]; }
        int i0 = 0;
#pragma unroll
        for (int e = 1; e < E_NUM; ++e) if (p[e] > p[i0]) i0 = e;
        int i1 = (i0 == 0) ? 1 : 0;
#pragma unroll
        for (int e = 0; e < E_NUM; ++e) if (e != i0 && p[e] > p[i1]) i1 = e;
        float s0 = p[i0] / s, s1 = p[i1] / s;
        float d = s0 + s1 + 1e-20f;
        int p0 = atomicAdd(&counts[i0], 1); if (p0 >= CAP) p0 = CAP - 1;
        int p1 = atomicAdd(&counts[i1], 1); if (p1 >= CAP) p1 = CAP - 1;
        slot0 = i0 * CAP + p0;
        slot1 = i1 * CAP + p1;
        stok[slot0] = t; sw[slot0] = s0 / d;
        stok[slot1] = t; sw[slot1] = s1 / d;
    }
    slot0 = __shfl(slot0, 0, 64);
    slot1 = __shfl(slot1, 0, 64);
    const float4* xr4 = (const float4*)xr;
    ushort4* xg4 = (ushort4*)xg;
#pragma unroll
    for (int it = 0; it < 4; ++it) {
        float4 v = xr4[lane + 64 * it];
        ushort4 o;
        o.x = f2bf(v.x); o.y = f2bf(v.y); o.z = f2bf(v.z); o.w = f2bf(v.w);
        xg4[(size_t)slot0 * 256 + lane + 64 * it] = o;
        xg4[(size_t)slot1 * 256 + lane + 64 * it] = o;
    }
}

// One K-step of GEMM1&3. Packs B(T+1) from regs P*, loads B(T+2) into regs Q*.
#define G13_STEP(T, P0, P1, P2, P3, Q0, Q1, Q2, Q3)                                   \
{                                                                                      \
    short8 a[4][2], b1[2][2], b3[2][2];                                                \
    _Pragma("unroll") for (int m = 0; m < 4; ++m) {                                    \
        const unsigned char* ab = As + agrp + m * 2048;                                \
        a[m][0] = *(const short8*)(ab + c0);                                           \
        a[m][1] = *(const short8*)(ab + c1);                                           \
    }                                                                                  \
    _Pragma("unroll") for (int n = 0; n < 2; ++n) {                                    \
        const int bg = (n * 2 + f8) * 1024 + f7 * 128;                                 \
        b1[n][0] = *(const short8*)(B1s + bg + c0);                                    \
        b1[n][1] = *(const short8*)(B1s + bg + c1);                                    \
        b3[n][0] = *(const short8*)(B3s + bg + c0);                                    \
        b3[n][1] = *(const short8*)(B3s + bg + c1);                                    \
    }                                                                                  \
    WAIT_LGKM0; SCHED0;                                                                \
    SBAR; SCHED0;                               /* #1: all waves done reading t */     \
    if ((T) + 1 < NT_) {                                                               \
        const int kn = ((T) + 1) * 64;                                                 \
        _Pragma("unroll") for (int j = 0; j < 8; ++j)                                  \
            gl2lds16(aBase + (size_t)j * 8 * LDK_ + kn, As + (wave * 8 + j) * 1024);   \
    }                                                                                  \
    SCHED0;                                                                            \
    if ((T) + 2 < NT_) {                                                               \
        const int k2 = ((T) + 2) * 64;                                                 \
        Q0 = *(const float4*)(w1p + k2);                                               \
        Q1 = *(const float4*)(w1p + k2 + 4);                                           \
        Q2 = *(const float4*)(w3p + k2);                                               \
        Q3 = *(const float4*)(w3p + k2 + 4);                                           \
    }                                                                                  \
    SCHED0;                                                                            \
    _Pragma("unroll") for (int m = 0; m < 4; ++m) {                                    \
        _Pragma("unroll") for (int n = 0; n < 2; ++n) {                                \
            acc1[m][n] = __builtin_amdgcn_mfma_f32_16x16x32_bf16(a[m][0], b1[n][0], acc1[m][n], 0, 0, 0); \
            acc1[m][n] = __builtin_amdgcn_mfma_f32_16x16x32_bf16(a[m][1], b1[n][1], acc1[m][n], 0, 0, 0); \
            acc3[m][n] = __builtin_amdgcn_mfma_f32_16x16x32_bf16(a[m][0], b3[n][0], acc3[m][n], 0, 0, 0); \
            acc3[m][n] = __builtin_amdgcn_mfma_f32_16x16x32_bf16(a[m][1], b3[n][1], acc3[m][n], 0, 0, 0); \
        }                                                                              \
    }                                                                                  \
    if ((T) + 1 < NT_) {                                                               \
        *(short8*)(B1s + bslot) = pack8r(P0, P1);                                      \
        *(short8*)(B3s + bslot) = pack8r(P2, P3);                                      \
        if ((T) + 2 < NT_) { WAIT_VM(4); } else { WAIT_VM(0); }                        \
        WAIT_LGKM0; SCHED0;                                                            \
        SBAR; SCHED0;                           /* #2: tile t+1 ready */               \
    }                                                                                  \
}

// ---- GEMM 1&3: BM=256, BN=32(W1)+32(W3), BK=64, counted-vmcnt pipeline ----
__global__ __launch_bounds__(256, 2) void k_gemm13(const unsigned short* __restrict__ xg,
                                                   const float* __restrict__ W1,
                                                   const float* __restrict__ W3,
                                                   const int* __restrict__ counts,
                                                   unsigned short* __restrict__ U) {
    const int nt = blockIdx.x;       // H/32 = 88
    const int mt = blockIdx.y;       // CAP/256 = 4
    const int e  = blockIdx.z;
    const int cnt = min(counts[e], CAP);
    if (mt * 256 >= cnt) return;

    __shared__ __align__(16) unsigned char As[32768];   // 256 rows x 64 bf16
    __shared__ __align__(16) unsigned char B1s[4096];   // 32 rows x 64 bf16
    __shared__ __align__(16) unsigned char B3s[4096];   // total 40960 B

    const int tid = threadIdx.x, lane = tid & 63, wave = tid >> 6;
    const int fr = lane & 15, quad = lane >> 4, f7 = fr & 7, f8 = fr >> 3;

    const unsigned short* aBase = xg
        + ((size_t)e * CAP + mt * 256 + wave * 64 + (lane >> 3)) * D_DIM
        + ((lane & 7) ^ (lane >> 3)) * 8;

    const int br = tid >> 3, bc = tid & 7;
    const float* w1p = W1 + ((size_t)e * H_DIM + nt * 32 + br) * D_DIM + bc * 8;
    const float* w3p = W3 + ((size_t)e * H_DIM + nt * 32 + br) * D_DIM + bc * 8;
    const int bslot = (br >> 3) * 1024 + (br & 7) * 128 + ((bc ^ (br & 7)) << 4);

    floatx4 acc1[4][2], acc3[4][2];
#pragma unroll
    for (int m = 0; m < 4; ++m)
#pragma unroll
        for (int n = 0; n < 2; ++n) { acc1[m][n] = (floatx4)0.f; acc3[m][n] = (floatx4)0.f; }

    const int agrp = (wave * 8 + f8) * 1024 + f7 * 128;
    const int c0 = (quad ^ f7) << 4;          // kk=0 chunk byte offset
    const int c1 = ((4 | quad) ^ f7) << 4;    // kk=1

    // ---- prologue: B(0) sync-load+pack, stage A(0), B(1) in flight across barrier ----
    float4 pA0, pA1, pA2, pA3, qA0, qA1, qA2, qA3;
    pA0 = *(const float4*)(w1p);
    pA1 = *(const float4*)(w1p + 4);
    pA2 = *(const float4*)(w3p);
    pA3 = *(const float4*)(w3p + 4);
    SCHED0;
#pragma unroll
    for (int j = 0; j < 8; ++j)
        gl2lds16(aBase + (size_t)j * 8 * D_DIM, As + (wave * 8 + j) * 1024);
    SCHED0;
    qA0 = *(const float4*)(w1p + 64);
    qA1 = *(const float4*)(w1p + 68);
    qA2 = *(const float4*)(w3p + 64);
    qA3 = *(const float4*)(w3p + 68);
    SCHED0;
    *(short8*)(B1s + bslot) = pack8r(pA0, pA1);    // auto-wait on pA regs only
    *(short8*)(B3s + bslot) = pack8r(pA2, pA3);
    WAIT_VM(4);           // A(0) staged; B(1) loads stay in flight
    WAIT_LGKM0; SCHED0;
    SBAR; SCHED0;

#define NT_  NT13
#define LDK_ D_DIM
#pragma unroll 1
    for (int t = 0; t < NT13; t += 2) {
        G13_STEP(t,     qA0, qA1, qA2, qA3, pA0, pA1, pA2, pA3);   // pack B(t+1)=q, load B(t+2)->p
        G13_STEP(t + 1, pA0, pA1, pA2, pA3, qA0, qA1, qA2, qA3);   // pack B(t+2)=p, load B(t+3)->q
    }
#undef NT_
#undef LDK_

#pragma unroll
    for (int m = 0; m < 4; ++m) {
#pragma unroll
        for (int r = 0; r < 4; ++r) {
            int g = mt * 256 + wave * 64 + m * 16 + quad * 4 + r;
            if (g < cnt) {
                size_t rowb = ((size_t)e * CAP + g) * H_DIM + nt * 32;
#pragma unroll
                for (int n = 0; n < 2; ++n) {
                    float u1v = acc1[m][n][r], u3v = acc3[m][n][r];
                    float u = u1v / (1.f + __expf(-u1v)) * u3v;
                    U[rowb + n * 16 + fr] = f2bf(u);
                }
            }
        }
    }
}

// One K-step of GEMM2 (BN=64): packs B(T+1) from P*, loads B(T+2) into Q*.
#define G2_STEP(T, P0, P1, P2, P3, Q0, Q1, Q2, Q3)                                     \
{                                                                                      \
    short8 a[4][2], bf[4][2];                                                          \
    _Pragma("unroll") for (int m = 0; m < 4; ++m) {                                    \
        const unsigned char* ab = As + agrp + m * 2048;                                \
        a[m][0] = *(const short8*)(ab + c0);                                           \
        a[m][1] = *(const short8*)(ab + c1);                                           \
    }                                                                                  \
    _Pragma("unroll") for (int n = 0; n < 4; ++n) {                                    \
        const int bg = (n * 2 + f8) * 1024 + f7 * 128;                                 \
        bf[n][0] = *(const short8*)(Bs + bg + c0);                                     \
        bf[n][1] = *(const short8*)(Bs + bg + c1);                                     \
    }                                                                                  \
    WAIT_LGKM0; SCHED0;                                                                \
    SBAR; SCHED0;                                                                      \
    if ((T) + 1 < NT2) {                                                               \
        const int kn = ((T) + 1) * 64;                                                 \
        _Pragma("unroll") for (int j = 0; j < 8; ++j)                                  \
            gl2lds16(aBase + (size_t)j * 8 * H_DIM + kn, As + (wave * 8 + j) * 1024);  \
    }                                                                                  \
    SCHED0;                                                                            \
    if ((T) + 2 < NT2) {                                                               \
        const int k2 = ((T) + 2) * 64;                                                 \
        Q0 = *(const float4*)(w2p0 + k2);                                              \
        Q1 = *(const float4*)(w2p0 + k2 + 4);                                          \
        Q2 = *(const float4*)(w2p1 + k2);                                              \
        Q3 = *(const float4*)(w2p1 + k2 + 4);                                          \
    }                                                                                  \
    SCHED0;                                                                            \
    _Pragma("unroll") for (int m = 0; m < 4; ++m) {                                    \
        _Pragma("unroll") for (int n = 0; n < 4; ++n) {                                \
            acc[m][n] = __builtin_amdgcn_mfma_f32_16x16x32_bf16(a[m][0], bf[n][0], acc[m][n], 0, 0, 0); \
            acc[m][n] = __builtin_amdgcn_mfma_f32_16x16x32_bf16(a[m][1], bf[n][1], acc[m][n], 0, 0, 0); \
        }                                                                              \
    }                                                                                  \
    if ((T) + 1 < NT2) {                                                               \
        *(short8*)(Bs + bslot0) = pack8r(P0, P1);                                      \
        *(short8*)(Bs + bslot1) = pack8r(P2, P3);                                      \
        if ((T) + 2 < NT2) { WAIT_VM(4); } else { WAIT_VM(0); }                        \
        WAIT_LGKM0; SCHED0;                                                            \
        SBAR; SCHED0;                                                                  \
    }                                                                                  \
}

// ---- GEMM 2: BM=256, BN=64, BK=64, K=2816; counted-vmcnt pipeline; atomic epilogue ----
__global__ __launch_bounds__(256, 2) void k_gemm2(const unsigned short* __restrict__ U,
                                                  const float* __restrict__ W2,
                                                  const int* __restrict__ counts,
                                                  const int* __restrict__ stok,
                                                  const float* __restrict__ sw,
                                                  float* __restrict__ y) {
    const int nt = blockIdx.x;       // D/64 = 16
    const int mt = blockIdx.y;       // CAP/256 = 4
    const int e  = blockIdx.z;
    const int cnt = min(counts[e], CAP);
    if (mt * 256 >= cnt) return;

    __shared__ __align__(16) unsigned char As[32768];   // 256 rows x 64 bf16
    __shared__ __align__(16) unsigned char Bs[8192];    // 64 w-rows; total 40960 B

    const int tid = threadIdx.x, lane = tid & 63, wave = tid >> 6;
    const int fr = lane & 15, quad = lane >> 4, f7 = fr & 7, f8 = fr >> 3;

    const unsigned short* aBase = U
        + ((size_t)e * CAP + mt * 256 + wave * 64 + (lane >> 3)) * H_DIM
        + ((lane & 7) ^ (lane >> 3)) * 8;

    const int br = tid >> 3, bc = tid & 7;       // rows br and br+32, chunk col bc
    const float* w2p0 = W2 + ((size_t)e * D_DIM + nt * 64 + br) * H_DIM + bc * 8;
    const float* w2p1 = w2p0 + (size_t)32 * H_DIM;
    const int bslot0 = (br >> 3) * 1024 + (br & 7) * 128 + ((bc ^ (br & 7)) << 4);
    const int bslot1 = bslot0 + 4096;            // (row+32)>>3 = +4 groups

    floatx4 acc[4][4];
#pragma unroll
    for (int m = 0; m < 4; ++m)
#pragma unroll
        for (int n = 0; n < 4; ++n) acc[m][n] = (floatx4)0.f;

    const int agrp = (wave * 8 + f8) * 1024 + f7 * 128;
    const int c0 = (quad ^ f7) << 4;
    const int c1 = ((4 | quad) ^ f7) << 4;

    // ---- prologue ----
    float4 pA0, pA1, pA2, pA3, qA0, qA1, qA2, qA3;
    pA0 = *(const float4*)(w2p0);
    pA1 = *(const float4*)(w2p0 + 4);
    pA2 = *(const float4*)(w2p1);
    pA3 = *(const float4*)(w2p1 + 4);
    SCHED0;
#pragma unroll
    for (int j = 0; j < 8; ++j)
        gl2lds16(aBase + (size_t)j * 8 * H_DIM, As + (wave * 8 + j) * 1024);
    SCHED0;
    qA0 = *(const float4*)(w2p0 + 64);
    qA1 = *(const float4*)(w2p0 + 68);
    qA2 = *(const float4*)(w2p1 + 64);
    qA3 = *(const float4*)(w2p1 + 68);
    SCHED0;
    *(short8*)(Bs + bslot0) = pack8r(pA0, pA1);
    *(short8*)(Bs + bslot1) = pack8r(pA2, pA3);
    WAIT_VM(4);           // A(0) staged; B(1) loads stay in flight
    WAIT_LGKM0; SCHED0;
    SBAR; SCHED0;

#pragma unroll 1
    for (int t = 0; t < NT2; t += 2) {
        G2_STEP(t,     qA0, qA1, qA2, qA3, pA0, pA1, pA2, pA3);
        G2_STEP(t + 1, pA0, pA1, pA2, pA3, qA0, qA1, qA2, qA3);
    }

#pragma unroll
    for (int m = 0; m < 4; ++m) {
#pragma unroll
        for (int r = 0; r < 4; ++r) {
            int g = mt * 256 + wave * 64 + m * 16 + quad * 4 + r;
            if (g < cnt) {
                int slot = e * CAP + g;
                int t = stok[slot];
                float w = sw[slot];
                float* yr = y + (size_t)t * D_DIM + nt * 64;
#pragma unroll
                for (int n = 0; n < 4; ++n)
                    atomicAdd(&yr[n * 16 + fr], w * acc[m][n][r]);
            }
        }
    }
}

// ---------------- workspace layout ----------------
static const size_t OFF_XG   = 0;                                   // 8*CAP*D*2 = 16,777,216
static const size_t OFF_U    = (size_t)E_NUM * CAP * D_DIM * 2;     // 8*CAP*H*2 = 46,137,344
static const size_t OFF_STOK = OFF_U + (size_t)E_NUM * CAP * H_DIM * 2;
static const size_t OFF_SW   = OFF_STOK + (size_t)E_NUM * CAP * 4;
static const size_t OFF_META = OFF_SW + (size_t)E_NUM * CAP * 4;

extern "C" void kernel_launch(void* const* d_in, const int* in_sizes, int n_in,
                              void* d_out, int out_size, void* d_ws, size_t ws_size,
                              hipStream_t stream) {
    const float* x  = (const float*)d_in[0];
    const float* Wg = (const float*)d_in[1];
    const float* W1 = (const float*)d_in[2];
    const float* W2 = (const float*)d_in[3];
    const float* W3 = (const float*)d_in[4];
    float* y = (float*)d_out;
    char* ws = (char*)d_ws;

    unsigned short* xg = (unsigned short*)(ws + OFF_XG);
    unsigned short* U  = (unsigned short*)(ws + OFF_U);
    int*   stok   = (int*)(ws + OFF_STOK);
    float* sw     = (float*)(ws + OFF_SW);
    int*   counts = (int*)(ws + OFF_META);

    hipMemsetAsync(counts, 0, 64, stream);
    hipMemsetAsync(y, 0, (size_t)T_TOK * D_DIM * sizeof(float), stream);

    k_gate2<<<T_TOK / 4, 256, 0, stream>>>(x, Wg, stok, sw, counts, xg);
    k_gemm13<<<dim3(H_DIM / 32, CAP / 256, E_NUM), 256, 0, stream>>>(xg, W1, W3, counts, U);
    k_gemm2<<<dim3(D_DIM / 64, CAP / 256, E_NUM), 256, 0, stream>>>(U, W2, counts, stok, sw, y);
}

// Round 7
// 411.515 us; speedup vs baseline: 2.4493x; 1.0463x over previous
//
#include <hip/hip_runtime.h>
#include <hip/hip_bf16.h>

#define T_TOK 2048
#define D_DIM 1024
#define H_DIM 2816
#define E_NUM 8
#define CAP   1024             // per-expert row capacity (mean load 512, ~24 sigma margin)

#define NT13  (D_DIM / 64)     // 16 K-steps
#define NT2H  (H_DIM / 128)    // 22 K-steps per kz half (1408/64)

typedef __attribute__((ext_vector_type(8))) short short8;
typedef __attribute__((ext_vector_type(4))) float floatx4;

__device__ __forceinline__ unsigned short f2bf(float f) {
    unsigned int b = __float_as_uint(f);
    b += 0x7FFFu + ((b >> 16) & 1u);   // round-to-nearest-even
    return (unsigned short)(b >> 16);
}

// pack 2 f32 -> 2 bf16 in one v_perm (round-half-up via +0x8000)
__device__ __forceinline__ unsigned pk2(float lo, float hi) {
    unsigned a = __float_as_uint(lo) + 0x8000u;
    unsigned b = __float_as_uint(hi) + 0x8000u;
    return __builtin_amdgcn_perm(b, a, 0x07060302);
}

__device__ __forceinline__ short8 pack8r(float4 a, float4 b) {
    union { uint4 u; short8 s; } r;
    r.u.x = pk2(a.x, a.y);
    r.u.y = pk2(a.z, a.w);
    r.u.z = pk2(b.x, b.y);
    r.u.w = pk2(b.z, b.w);
    return r.s;
}

// async 16B global->LDS. LDS dest = wave-uniform base + lane*16.
__device__ __forceinline__ void gl2lds16(const void* g, void* l) {
    __builtin_amdgcn_global_load_lds(
        (const __attribute__((address_space(1))) unsigned int*)g,
        (__attribute__((address_space(3))) unsigned int*)l,
        16, 0, 0);
}

#define SCHED0 __builtin_amdgcn_sched_barrier(0)

// Swizzled LDS tile layout (rows of 64 bf16 = 8 chunks of 16B), unpadded:
//   byte(row, slot) = (row>>3)*1024 + (row&7)*128 + slot*16
//   content(row, slot) = global chunk (slot ^ (row&7)).   0 bank conflicts (measured r2/r3/r6).
//
// r6 lesson: counted-vmcnt == __syncthreads schedule (116 vs 113 us) -> the wall is the
// fixed per-K-step serial skeleton, not the waits. r7 amortizes it: 64 MFMA per
// barrier-pair (g13 BN=64 dual) and restores g2 TLP via K-split (was 1 block/CU).
// Per-step order: [B(t+1) f32 loads: oldest vmem] [kk0 frags+MFMA] [kk1 frags]
//   SYNC [gl2lds A(t+1)] [kk1 MFMA covers it] [pack B(t+1): vmcnt leaves gl2lds] SYNC.

// ---- fused gate: logits -> softmax -> top2 -> scatter-gather x into slots ----
__global__ __launch_bounds__(256) void k_gate2(const float* __restrict__ x,
                                               const float* __restrict__ Wg,
                                               int* __restrict__ stok,
                                               float* __restrict__ sw,
                                               int* __restrict__ counts,
                                               unsigned short* __restrict__ xg) {
    const int wave = threadIdx.x >> 6, lane = threadIdx.x & 63;
    const int t = blockIdx.x * 4 + wave;
    const float* xr = x + (size_t)t * D_DIM;
    float acc[E_NUM];
#pragma unroll
    for (int e = 0; e < E_NUM; ++e) acc[e] = 0.f;
#pragma unroll 4
    for (int i = 0; i < D_DIM / 64; ++i) {
        float xv = xr[lane + 64 * i];
#pragma unroll
        for (int e = 0; e < E_NUM; ++e) acc[e] += xv * Wg[e * D_DIM + lane + 64 * i];
    }
#pragma unroll
    for (int e = 0; e < E_NUM; ++e) {
#pragma unroll
        for (int s = 32; s > 0; s >>= 1) acc[e] += __shfl_xor(acc[e], s, 64);
    }
    int slot0 = 0, slot1 = 0;
    if (lane == 0) {
        float mx = acc[0];
#pragma unroll
        for (int e = 1; e < E_NUM; ++e) mx = fmaxf(mx, acc[e]);
        float p[E_NUM], s = 0.f;
#pragma unroll
        for (int e = 0; e < E_NUM; ++e) { p[e] = __expf(acc[e] - mx); s += p[e]; }
        int i0 = 0;
#pragma unroll
        for (int e = 1; e < E_NUM; ++e) if (p[e] > p[i0]) i0 = e;
        int i1 = (i0 == 0) ? 1 : 0;
#pragma unroll
        for (int e = 0; e < E_NUM; ++e) if (e != i0 && p[e] > p[i1]) i1 = e;
        float s0 = p[i0] / s, s1 = p[i1] / s;
        float d = s0 + s1 + 1e-20f;
        int p0 = atomicAdd(&counts[i0], 1); if (p0 >= CAP) p0 = CAP - 1;
        int p1 = atomicAdd(&counts[i1], 1); if (p1 >= CAP) p1 = CAP - 1;
        slot0 = i0 * CAP + p0;
        slot1 = i1 * CAP + p1;
        stok[slot0] = t; sw[slot0] = s0 / d;
        stok[slot1] = t; sw[slot1] = s1 / d;
    }
    slot0 = __shfl(slot0, 0, 64);
    slot1 = __shfl(slot1, 0, 64);
    const float4* xr4 = (const float4*)xr;
    ushort4* xg4 = (ushort4*)xg;
#pragma unroll
    for (int it = 0; it < 4; ++it) {
        float4 v = xr4[lane + 64 * it];
        ushort4 o;
        o.x = f2bf(v.x); o.y = f2bf(v.y); o.z = f2bf(v.z); o.w = f2bf(v.w);
        xg4[(size_t)slot0 * 256 + lane + 64 * it] = o;
        xg4[(size_t)slot1 * 256 + lane + 64 * it] = o;
    }
}

// ---- GEMM 1&3: BM=256, BN=64(W1)+64(W3), BK=64; 64 MFMA per barrier-pair ----
__global__ __launch_bounds__(256, 2) void k_gemm13(const unsigned short* __restrict__ xg,
                                                   const float* __restrict__ W1,
                                                   const float* __restrict__ W3,
                                                   const int* __restrict__ counts,
                                                   unsigned short* __restrict__ U) {
    const int nt = blockIdx.x;       // H/64 = 44
    const int mt = blockIdx.y;       // CAP/256 = 4
    const int e  = blockIdx.z;
    const int cnt = min(counts[e], CAP);
    if (mt * 256 >= cnt) return;

    __shared__ __align__(16) unsigned char As[32768];   // 256 rows x 64 bf16
    __shared__ __align__(16) unsigned char B1s[8192];   // 64 rows x 64 bf16
    __shared__ __align__(16) unsigned char B3s[8192];   // total 49152 B -> 2 blocks/CU

    const int tid = threadIdx.x, lane = tid & 63, wave = tid >> 6;
    const int fr = lane & 15, quad = lane >> 4, f7 = fr & 7, f8 = fr >> 3;

    const unsigned short* aBase = xg
        + ((size_t)e * CAP + mt * 256 + wave * 64 + (lane >> 3)) * D_DIM
        + ((lane & 7) ^ (lane >> 3)) * 8;

    const int br = tid >> 3, bc = tid & 7;   // B rows br and br+32, chunk col bc
    const float* w1p = W1 + ((size_t)e * H_DIM + nt * 64 + br) * D_DIM + bc * 8;
    const float* w3p = W3 + ((size_t)e * H_DIM + nt * 64 + br) * D_DIM + bc * 8;
    const int bslot = (br >> 3) * 1024 + (br & 7) * 128 + ((bc ^ (br & 7)) << 4);
    // row br+32 -> bslot + 4096

    floatx4 acc1[4][4], acc3[4][4];
#pragma unroll
    for (int m = 0; m < 4; ++m)
#pragma unroll
        for (int n = 0; n < 4; ++n) { acc1[m][n] = (floatx4)0.f; acc3[m][n] = (floatx4)0.f; }

    const int agrp = (wave * 8 + f8) * 1024 + f7 * 128;
    const int c0 = (quad ^ f7) << 4;          // kk=0 chunk byte offset
    const int c1 = ((4 | quad) ^ f7) << 4;    // kk=1

    // ---- prologue: B(0) loads (oldest), A(0) gl2lds, pack B(0) [vmcnt leaves gl2lds] ----
    {
        float4 u0 = *(const float4*)(w1p);
        float4 u1 = *(const float4*)(w1p + 4);
        float4 u2 = *(const float4*)(w1p + (size_t)32 * D_DIM);
        float4 u3 = *(const float4*)(w1p + (size_t)32 * D_DIM + 4);
        float4 v0 = *(const float4*)(w3p);
        float4 v1 = *(const float4*)(w3p + 4);
        float4 v2 = *(const float4*)(w3p + (size_t)32 * D_DIM);
        float4 v3 = *(const float4*)(w3p + (size_t)32 * D_DIM + 4);
        SCHED0;
#pragma unroll
        for (int j = 0; j < 8; ++j)
            gl2lds16(aBase + (size_t)j * 8 * D_DIM, As + (wave * 8 + j) * 1024);
        SCHED0;
        *(short8*)(B1s + bslot)        = pack8r(u0, u1);
        *(short8*)(B1s + bslot + 4096) = pack8r(u2, u3);
        *(short8*)(B3s + bslot)        = pack8r(v0, v1);
        *(short8*)(B3s + bslot + 4096) = pack8r(v2, v3);
    }
    __syncthreads();

#pragma unroll 1
    for (int t = 0; t < NT13; ++t) {
        const bool more = (t + 1 < NT13);
        // ---- B(t+1) global loads FIRST (oldest in vmcnt queue; ~full step of cover) ----
        float4 u0, u1, u2, u3, v0, v1, v2, v3;
        if (more) {
            const int kn = (t + 1) * 64;
            u0 = *(const float4*)(w1p + kn);
            u1 = *(const float4*)(w1p + kn + 4);
            u2 = *(const float4*)(w1p + (size_t)32 * D_DIM + kn);
            u3 = *(const float4*)(w1p + (size_t)32 * D_DIM + kn + 4);
            v0 = *(const float4*)(w3p + kn);
            v1 = *(const float4*)(w3p + kn + 4);
            v2 = *(const float4*)(w3p + (size_t)32 * D_DIM + kn);
            v3 = *(const float4*)(w3p + (size_t)32 * D_DIM + kn + 4);
        }
        SCHED0;

        // ---- kk=0: frags + 32 MFMA ----
        {
            short8 a[4], b1[4], b3[4];
#pragma unroll
            for (int m = 0; m < 4; ++m)
                a[m] = *(const short8*)(As + agrp + m * 2048 + c0);
#pragma unroll
            for (int n = 0; n < 4; ++n) {
                const int bg = (n * 2 + f8) * 1024 + f7 * 128;
                b1[n] = *(const short8*)(B1s + bg + c0);
                b3[n] = *(const short8*)(B3s + bg + c0);
            }
#pragma unroll
            for (int m = 0; m < 4; ++m)
#pragma unroll
                for (int n = 0; n < 4; ++n) {
                    acc1[m][n] = __builtin_amdgcn_mfma_f32_16x16x32_bf16(a[m], b1[n], acc1[m][n], 0, 0, 0);
                    acc3[m][n] = __builtin_amdgcn_mfma_f32_16x16x32_bf16(a[m], b3[n], acc3[m][n], 0, 0, 0);
                }
        }

        // ---- kk=1: frags (before barrier), MFMA after (covers gl2lds) ----
        short8 a1[4], b11[4], b31[4];
#pragma unroll
        for (int m = 0; m < 4; ++m)
            a1[m] = *(const short8*)(As + agrp + m * 2048 + c1);
#pragma unroll
        for (int n = 0; n < 4; ++n) {
            const int bg = (n * 2 + f8) * 1024 + f7 * 128;
            b11[n] = *(const short8*)(B1s + bg + c1);
            b31[n] = *(const short8*)(B3s + bg + c1);
        }
        __syncthreads();   // all reads of tile t done; As/B safe to overwrite

        if (more) {
            const int kn = (t + 1) * 64;
#pragma unroll
            for (int j = 0; j < 8; ++j)
                gl2lds16(aBase + (size_t)j * 8 * D_DIM + kn, As + (wave * 8 + j) * 1024);
        }
        SCHED0;

#pragma unroll
        for (int m = 0; m < 4; ++m)
#pragma unroll
            for (int n = 0; n < 4; ++n) {
                acc1[m][n] = __builtin_amdgcn_mfma_f32_16x16x32_bf16(a1[m], b11[n], acc1[m][n], 0, 0, 0);
                acc3[m][n] = __builtin_amdgcn_mfma_f32_16x16x32_bf16(a1[m], b31[n], acc3[m][n], 0, 0, 0);
            }

        if (more) {
            *(short8*)(B1s + bslot)        = pack8r(u0, u1);   // waits B only (older than gl2lds)
            *(short8*)(B1s + bslot + 4096) = pack8r(u2, u3);
            *(short8*)(B3s + bslot)        = pack8r(v0, v1);
            *(short8*)(B3s + bslot + 4096) = pack8r(v2, v3);
            __syncthreads();   // tile t+1 ready
        }
    }

#pragma unroll
    for (int m = 0; m < 4; ++m) {
#pragma unroll
        for (int r = 0; r < 4; ++r) {
            int g = mt * 256 + wave * 64 + m * 16 + quad * 4 + r;
            if (g < cnt) {
                size_t rowb = ((size_t)e * CAP + g) * H_DIM + nt * 64;
#pragma unroll
                for (int n = 0; n < 4; ++n) {
                    float u1v = acc1[m][n][r], u3v = acc3[m][n][r];
                    float u = u1v / (1.f + __expf(-u1v)) * u3v;
                    U[rowb + n * 16 + fr] = f2bf(u);
                }
            }
        }
    }
}

// ---- GEMM 2: BM=256, BN=64, BK=64, K split in 2 halves (kz) for 2 blocks/CU TLP ----
__global__ __launch_bounds__(256, 2) void k_gemm2(const unsigned short* __restrict__ U,
                                                  const float* __restrict__ W2,
                                                  const int* __restrict__ counts,
                                                  const int* __restrict__ stok,
                                                  const float* __restrict__ sw,
                                                  float* __restrict__ y) {
    const int nt = blockIdx.x >> 1;  // D/64 = 16
    const int kz = blockIdx.x & 1;   // K half: 0 -> [0,1408), 1 -> [1408,2816)
    const int mt = blockIdx.y;       // CAP/256 = 4
    const int e  = blockIdx.z;
    const int cnt = min(counts[e], CAP);
    if (mt * 256 >= cnt) return;

    __shared__ __align__(16) unsigned char As[32768];   // 256 rows x 64 bf16
    __shared__ __align__(16) unsigned char Bs[8192];    // 64 w-rows; total 40960 B

    const int tid = threadIdx.x, lane = tid & 63, wave = tid >> 6;
    const int fr = lane & 15, quad = lane >> 4, f7 = fr & 7, f8 = fr >> 3;
    const int kbase = kz * (H_DIM / 2);                 // 1408 (multiple of 64)

    const unsigned short* aBase = U
        + ((size_t)e * CAP + mt * 256 + wave * 64 + (lane >> 3)) * H_DIM
        + ((lane & 7) ^ (lane >> 3)) * 8 + kbase;

    const int br = tid >> 3, bc = tid & 7;       // rows br and br+32, chunk col bc
    const float* w2p0 = W2 + ((size_t)e * D_DIM + nt * 64 + br) * H_DIM + bc * 8 + kbase;
    const float* w2p1 = w2p0 + (size_t)32 * H_DIM;
    const int bslot0 = (br >> 3) * 1024 + (br & 7) * 128 + ((bc ^ (br & 7)) << 4);
    const int bslot1 = bslot0 + 4096;            // (row+32)>>3 = +4 groups

    floatx4 acc[4][4];
#pragma unroll
    for (int m = 0; m < 4; ++m)
#pragma unroll
        for (int n = 0; n < 4; ++n) acc[m][n] = (floatx4)0.f;

    const int agrp = (wave * 8 + f8) * 1024 + f7 * 128;
    const int c0 = (quad ^ f7) << 4;
    const int c1 = ((4 | quad) ^ f7) << 4;

    // ---- prologue: stage tile 0 of this K half ----
    {
        float4 u0 = *(const float4*)(w2p0);
        float4 u1 = *(const float4*)(w2p0 + 4);
        float4 v0 = *(const float4*)(w2p1);
        float4 v1 = *(const float4*)(w2p1 + 4);
        SCHED0;
#pragma unroll
        for (int j = 0; j < 8; ++j)
            gl2lds16(aBase + (size_t)j * 8 * H_DIM, As + (wave * 8 + j) * 1024);
        SCHED0;
        *(short8*)(Bs + bslot0) = pack8r(u0, u1);
        *(short8*)(Bs + bslot1) = pack8r(v0, v1);
    }
    __syncthreads();

#pragma unroll 1
    for (int t = 0; t < NT2H; ++t) {
        const bool more = (t + 1 < NT2H);
        float4 u0, u1, v0, v1;
        if (more) {
            const int kn = (t + 1) * 64;
            u0 = *(const float4*)(w2p0 + kn);
            u1 = *(const float4*)(w2p0 + kn + 4);
            v0 = *(const float4*)(w2p1 + kn);
            v1 = *(const float4*)(w2p1 + kn + 4);
        }
        SCHED0;

        // ---- read ALL fragments of tile t ----
        short8 a[4][2], bf[4][2];
#pragma unroll
        for (int m = 0; m < 4; ++m) {
            const unsigned char* ab = As + agrp + m * 2048;
            a[m][0] = *(const short8*)(ab + c0);
            a[m][1] = *(const short8*)(ab + c1);
        }
#pragma unroll
        for (int n = 0; n < 4; ++n) {
            const int bg = (n * 2 + f8) * 1024 + f7 * 128;
            bf[n][0] = *(const short8*)(Bs + bg + c0);
            bf[n][1] = *(const short8*)(Bs + bg + c1);
        }
        __syncthreads();   // all waves done reading tile t

        if (more) {
            const int kn = (t + 1) * 64;
#pragma unroll
            for (int j = 0; j < 8; ++j)
                gl2lds16(aBase + (size_t)j * 8 * H_DIM + kn, As + (wave * 8 + j) * 1024);
        }
        SCHED0;

        // ---- 32 MFMAs (cover gl2lds) ----
#pragma unroll
        for (int m = 0; m < 4; ++m)
#pragma unroll
            for (int n = 0; n < 4; ++n) {
                acc[m][n] = __builtin_amdgcn_mfma_f32_16x16x32_bf16(a[m][0], bf[n][0], acc[m][n], 0, 0, 0);
                acc[m][n] = __builtin_amdgcn_mfma_f32_16x16x32_bf16(a[m][1], bf[n][1], acc[m][n], 0, 0, 0);
            }

        if (more) {
            *(short8*)(Bs + bslot0) = pack8r(u0, u1);   // waits B only (older than gl2lds)
            *(short8*)(Bs + bslot1) = pack8r(v0, v1);
            __syncthreads();   // tile t+1 ready
        }
    }

    // ---- epilogue: weighted atomic combine (K-partials add correctly) ----
#pragma unroll
    for (int m = 0; m < 4; ++m) {
#pragma unroll
        for (int r = 0; r < 4; ++r) {
            int g = mt * 256 + wave * 64 + m * 16 + quad * 4 + r;
            if (g < cnt) {
                int slot = e * CAP + g;
                int t = stok[slot];
                float w = sw[slot];
                float* yr = y + (size_t)t * D_DIM + nt * 64;
#pragma unroll
                for (int n = 0; n < 4; ++n)
                    atomicAdd(&yr[n * 16 + fr], w * acc[m][n][r]);
            }
        }
    }
}

// ---------------- workspace layout ----------------
static const size_t OFF_XG   = 0;                                   // 8*CAP*D*2 = 16,777,216
static const size_t OFF_U    = (size_t)E_NUM * CAP * D_DIM * 2;     // 8*CAP*H*2 = 46,137,344
static const size_t OFF_STOK = OFF_U + (size_t)E_NUM * CAP * H_DIM * 2;
static const size_t OFF_SW   = OFF_STOK + (size_t)E_NUM * CAP * 4;
static const size_t OFF_META = OFF_SW + (size_t)E_NUM * CAP * 4;

extern "C" void kernel_launch(void* const* d_in, const int* in_sizes, int n_in,
                              void* d_out, int out_size, void* d_ws, size_t ws_size,
                              hipStream_t stream) {
    const float* x  = (const float*)d_in[0];
    const float* Wg = (const float*)d_in[1];
    const float* W1 = (const float*)d_in[2];
    const float* W2 = (const float*)d_in[3];
    const float* W3 = (const float*)d_in[4];
    float* y = (float*)d_out;
    char* ws = (char*)d_ws;

    unsigned short* xg = (unsigned short*)(ws + OFF_XG);
    unsigned short* U  = (unsigned short*)(ws + OFF_U);
    int*   stok   = (int*)(ws + OFF_STOK);
    float* sw     = (float*)(ws + OFF_SW);
    int*   counts = (int*)(ws + OFF_META);

    hipMemsetAsync(counts, 0, 64, stream);
    hipMemsetAsync(y, 0, (size_t)T_TOK * D_DIM * sizeof(float), stream);

    k_gate2<<<T_TOK / 4, 256, 0, stream>>>(x, Wg, stok, sw, counts, xg);
    k_gemm13<<<dim3(H_DIM / 64, CAP / 256, E_NUM), 256, 0, stream>>>(xg, W1, W3, counts, U);
    k_gemm2<<<dim3(2 * D_DIM / 64, CAP / 256, E_NUM), 256, 0, stream>>>(U, W2, counts, stok, sw, y);
}